// Round 6
// baseline (645.913 us; speedup 1.0000x reference)
//
#include <hip/hip_runtime.h>

typedef __attribute__((ext_vector_type(8))) short short8;
typedef __attribute__((ext_vector_type(4))) float float4v;
typedef unsigned int u32;

#define K_DIM 4096
#define O_DIM 11008
#define KP    2048   // packed int32 per output row (1 byte of codes per int32)
#define NBLK  64     // absmax blocks per row
#define BK    64
#define NT2   (K_DIM / BK)   // 64 K-tiles
#define BM2   256
#define BN2   256
// fused-fallback geometry
#define BM    128
#define BN    128
#define LDT   72

// NF4 table via immediate-literal select tree (no device globals).
__device__ __forceinline__ float nf4_val(int c) {
    float v = -1.0f;
    v = (c == 1)  ? -0.6961928009986877f   : v;
    v = (c == 2)  ? -0.5250730514526367f   : v;
    v = (c == 3)  ? -0.39491748809814453f  : v;
    v = (c == 4)  ? -0.28444138169288635f  : v;
    v = (c == 5)  ? -0.18477343022823334f  : v;
    v = (c == 6)  ? -0.09105003625154495f  : v;
    v = (c == 7)  ? 0.0f                   : v;
    v = (c == 8)  ? 0.07958029955625534f   : v;
    v = (c == 9)  ? 0.16093020141124725f   : v;
    v = (c == 10) ? 0.24611230194568634f   : v;
    v = (c == 11) ? 0.33791524171829224f   : v;
    v = (c == 12) ? 0.44070982933044434f   : v;
    v = (c == 13) ? 0.5626170039176941f    : v;
    v = (c == 14) ? 0.8072066307067871f    : v;
    v = (c == 15) ? 1.0f                   : v;
    return v;
}

__device__ __forceinline__ unsigned short bf16_rne(float f) {
    unsigned int u = __float_as_uint(f);
    u = (u + 0x7FFFu + ((u >> 16) & 1u)) >> 16;
    return (unsigned short)u;
}

__device__ __forceinline__ unsigned int pack_bf16x2(float lo_k, float hi_k) {
    return (unsigned int)bf16_rne(lo_k) | ((unsigned int)bf16_rne(hi_k) << 16);
}

// async global->LDS, 16 B per lane; LDS dest is wave-uniform base + lane*16.
__device__ __forceinline__ void gload_lds16(const unsigned short* g, unsigned short* l) {
    __builtin_amdgcn_global_load_lds((const __attribute__((address_space(1))) u32*)g,
                                     (__attribute__((address_space(3))) u32*)l,
                                     16, 0, 0);
}

// ---------------------------------------------------------------------------
// Fused prep: (a) NF4 W -> bf16 (dequantized ONCE), (b) X f32 -> bf16.
// ---------------------------------------------------------------------------
__global__ __launch_bounds__(256) void prep_kernel(
    const float* __restrict__ X, unsigned short* __restrict__ Xb, int nchunk_x,
    const int* __restrict__ Wp, const float* __restrict__ Smax,
    unsigned short* __restrict__ Wb, int nchunk_w)
{
    __shared__ unsigned int T2[256];   // byte -> packed bf16 pair (unscaled)
    {
        const int t = threadIdx.x;
        unsigned int hi = (unsigned int)bf16_rne(nf4_val(t >> 4));
        unsigned int lo = (unsigned int)bf16_rne(nf4_val(t & 15));
        T2[t] = hi | (lo << 16);
    }
    __syncthreads();

    const int stride = gridDim.x * 256;
    const int g0 = blockIdx.x * 256 + threadIdx.x;

    for (int idx = g0; idx < nchunk_w; idx += stride) {
        const int row = idx >> 9;        // output row
        const int c   = idx & 511;       // 16B chunk within row (8 bf16 out)

        uint4 wv = *(const uint4*)(Wp + (size_t)row * KP + c * 4);
        const float s0 = Smax[row * NBLK + (c >> 3)];
        unsigned int vv[4] = {wv.x, wv.y, wv.z, wv.w};
        unsigned int od[4];
#pragma unroll
        for (int j = 0; j < 4; ++j) {
            const unsigned int pair = T2[vv[j] & 0xFFu];
            const float fe = __uint_as_float(pair << 16) * s0;           // k even (hi nibble)
            const float fo = __uint_as_float(pair & 0xFFFF0000u) * s0;   // k odd  (lo nibble)
            od[j] = pack_bf16x2(fe, fo);
        }
        uint4 ov; ov.x = od[0]; ov.y = od[1]; ov.z = od[2]; ov.w = od[3];
        *(uint4*)(Wb + (size_t)row * K_DIM + c * 8) = ov;
    }

    for (int i = g0; i < nchunk_x; i += stride) {
        const float* p = X + (size_t)i * 8;
        float4v a = *(const float4v*)p;
        float4v b = *(const float4v*)(p + 4);
        uint4 o;
        o.x = pack_bf16x2(a.x, a.y);
        o.y = pack_bf16x2(a.z, a.w);
        o.z = pack_bf16x2(b.x, b.y);
        o.w = pack_bf16x2(b.z, b.w);
        *(uint4*)(Xb + (size_t)i * 8) = o;
    }
}

// ---------------------------------------------------------------------------
// Main GEMM: 256x256 tile, 8-wave, 8-phase counted-vmcnt schedule (T3+T4),
// XOR slot-swizzle (T2), setprio (T5), XCD swizzle (T1).
//
// Round-6 = round-5 performance changes with fencing trimmed to the verified
// m201 phase template (m141 lesson: don't order-pin both phase ends):
//  * phase start: s_barrier; s_waitcnt lgkmcnt(0); sched_barrier(0)  [rule #18]
//  * phase end:   s_barrier only
//  * K-loop unrolled x2 -> double-buffer index is a literal; fragment reads
//    are base-VGPR + compile-time imm offsets via pA0/pA1/pB0/pB1
//    (kills per-phase VALU address chains; VALUBusy 16% -> target ~10%).
//
// LDS map (shorts): buf b (0/1) at b*32768; A k-half h at h*8192,
// B at +16384; row*32 + slot*8.  Swizzle: slot' = slot ^ ((row>>1)&3)
// (2-way max on both gload_lds-write and ds_read sides; 0 conflicts, R4).
//
// Ledger (per K-tile u, buf b=u&1): P1 reads (b,h0) mh0, stages (u+1,A,k1);
// P2 reads (b,h0) mh1, stages (u+1,B,k1), vmcnt(8); P3 reads (b,h1) mh0,
// stages (u+2,A,k0); P4 reads (b,h1) mh1, stages (u+2,B,k0), vmcnt(8).
// Tails: vmcnt(8)/vmcnt(4), then vmcnt(0)/none.  Verified R3/R4 (absmax 0.5).
// ---------------------------------------------------------------------------
#define VMW8 asm volatile("s_waitcnt vmcnt(8)" ::: "memory")
#define VMW4 asm volatile("s_waitcnt vmcnt(4)" ::: "memory")
#define VMW0 asm volatile("s_waitcnt vmcnt(0)" ::: "memory")
#define VMWNONE ((void)0)

#define PH_BEGIN do { __builtin_amdgcn_s_barrier();                               \
        asm volatile("s_waitcnt lgkmcnt(0)" ::: "memory");                        \
        __builtin_amdgcn_sched_barrier(0); } while (0)
#define PH_END   __builtin_amdgcn_s_barrier()

__global__ __launch_bounds__(512, 2) void gemm_bf16_256(
    const unsigned short* __restrict__ Xb,   // [M][4096] bf16
    const unsigned short* __restrict__ Wb,   // [11008][4096] bf16
    const float* __restrict__ Bias,
    float* __restrict__ Out, int M)
{
    __shared__ unsigned short L[65536];   // 128 KiB

    const int t    = threadIdx.x;
    const int lane = t & 63;
    const int w    = t >> 6;             // 8 waves

    // XCD swizzle (gridDim.x divisible by 8)
    const int nm  = M / BM2;             // 16
    const int nwg = gridDim.x;           // 688
    const int wg  = (blockIdx.x & 7) * (nwg >> 3) + (blockIdx.x >> 3);
    const int m0  = (wg % nm) * BM2;
    const int n0  = (wg / nm) * BN2;

    const int wm = (w >> 2) * 128;       // wave M window (0/128)
    const int wn = (w & 3) * 64;         // wave N window (0..192)

    // staging: wave w stages rows [32w, 32w+32); lane -> (row=lane>>2,
    // slot=lane&3); source slot pre-swizzled with ((row>>1)&3).
    const int srow  = lane >> 2;
    const int sslot = (lane & 3) ^ ((lane >> 3) & 3);
    const unsigned short* srcA = Xb + (size_t)(m0 + w * 32 + srow) * K_DIM + sslot * 8;
    const unsigned short* srcB = Wb + (size_t)(n0 + w * 32 + srow) * K_DIM + sslot * 8;
    unsigned short* ldsA = &L[w * 1024];
    unsigned short* ldsB = &L[16384 + w * 1024];

    // fragment reads: row = (wm|wn) + f*16 + (lane&15); wanted slot = lane>>4;
    // stored slot = (lane>>4) ^ ((lane>>1)&3).  Four base pointers so every
    // frag access is base + compile-time imm.
    const int rrow  = lane & 15;
    const int rslot = ((lane >> 4) ^ ((lane >> 1) & 3)) * 8;
    const unsigned short* pA0 = &L[(wm + rrow) * 32 + rslot];
    const unsigned short* pA1 = pA0 + 32768;
    const unsigned short* pB0 = &L[16384 + (wn + rrow) * 32 + rslot];
    const unsigned short* pB1 = pB0 + 32768;

#define STAGE(src, ldsbase, bufh, koff)                                          \
    do {                                                                         \
        gload_lds16((src) + (koff), (ldsbase) + (bufh));                         \
        gload_lds16((src) + 16 * K_DIM + (koff), (ldsbase) + (bufh) + 512);      \
    } while (0)

#define AFRAG(b, h, mf) (*(const short8*)(((b) ? pA1 : pA0) + (h) * 8192 + (mf) * 512))
#define BFRAG(b, h, nf) (*(const short8*)(((b) ? pB1 : pB0) + (h) * 8192 + (nf) * 512))

    float4v acc[8][4] = {};
    short8 af[4], bf[4];

#define MFMA_Q(mbase)                                                             \
    __builtin_amdgcn_s_setprio(1);                                                \
    _Pragma("unroll") for (int mf = 0; mf < 4; ++mf)                              \
        _Pragma("unroll") for (int nf = 0; nf < 4; ++nf)                          \
            acc[(mbase) + mf][nf] = __builtin_amdgcn_mfma_f32_16x16x32_bf16(      \
                af[mf], bf[nf], acc[(mbase) + mf][nf], 0, 0, 0);                  \
    __builtin_amdgcn_s_setprio(0)

// b_ MUST be a literal 0/1 (== u_&1) so all LDS addressing is immediate.
#define KTILE(u_, b_, S12_, S34_, VM2_, VM4_)                                     \
    {                                                                             \
        const int kt_ = (u_) * BK;                                                \
        /* P1: h0, mh0 */                                                         \
        _Pragma("unroll") for (int nf = 0; nf < 4; ++nf) bf[nf] = BFRAG(b_, 0, nf); \
        _Pragma("unroll") for (int mf = 0; mf < 4; ++mf) af[mf] = AFRAG(b_, 0, mf); \
        if (S12_) STAGE(srcA, ldsA, ((b_) ^ 1) * 32768 + 8192, kt_ + BK + 32);    \
        PH_BEGIN;                                                                 \
        MFMA_Q(0);                                                                \
        PH_END;                                                                   \
        /* P2: h0, mh1 */                                                         \
        _Pragma("unroll") for (int mf = 0; mf < 4; ++mf) af[mf] = AFRAG(b_, 0, mf + 4); \
        if (S12_) STAGE(srcB, ldsB, ((b_) ^ 1) * 32768 + 8192, kt_ + BK + 32);    \
        PH_BEGIN;                                                                 \
        MFMA_Q(4);                                                                \
        VM2_;                                                                     \
        PH_END;                                                                   \
        /* P3: h1, mh0 */                                                         \
        _Pragma("unroll") for (int nf = 0; nf < 4; ++nf) bf[nf] = BFRAG(b_, 1, nf); \
        _Pragma("unroll") for (int mf = 0; mf < 4; ++mf) af[mf] = AFRAG(b_, 1, mf); \
        if (S34_) STAGE(srcA, ldsA, (b_) * 32768, kt_ + 2 * BK);                  \
        PH_BEGIN;                                                                 \
        MFMA_Q(0);                                                                \
        PH_END;                                                                   \
        /* P4: h1, mh1 */                                                         \
        _Pragma("unroll") for (int mf = 0; mf < 4; ++mf) af[mf] = AFRAG(b_, 1, mf + 4); \
        if (S34_) STAGE(srcB, ldsB, (b_) * 32768, kt_ + 2 * BK);                  \
        PH_BEGIN;                                                                 \
        MFMA_Q(4);                                                                \
        VM4_;                                                                     \
        PH_END;                                                                   \
    }

    // ---- prologue: stage (0,k0),(0,k1),(1,k0); retire (0,*); barrier ----
    STAGE(srcA, ldsA, 0,            0);    // (0,A,k0)
    STAGE(srcB, ldsB, 0,            0);    // (0,B,k0)
    STAGE(srcA, ldsA, 8192,         32);   // (0,A,k1)
    STAGE(srcB, ldsB, 8192,         32);   // (0,B,k1)
    STAGE(srcA, ldsA, 32768,        64);   // (1,A,k0)
    STAGE(srcB, ldsB, 32768,        64);   // (1,B,k0)
    VMW8;
    __builtin_amdgcn_s_barrier();

    // ---- steady loop (unrolled x2 so buffer index is literal) + tails ----
    for (int u = 0; u < NT2 - 2; u += 2) {
        KTILE(u,     0, true, true, VMW8, VMW8);
        KTILE(u + 1, 1, true, true, VMW8, VMW8);
    }
    KTILE(NT2 - 2, 0, true, false, VMW8, VMW4);
    KTILE(NT2 - 1, 1, false, false, VMW0, VMWNONE);

    // ---- epilogue: D col = lane&15, row = (lane>>4)*4 + reg ----
#pragma unroll
    for (int nf = 0; nf < 4; ++nf) {
        const int col = n0 + wn + nf * 16 + (lane & 15);
        const float bj = Bias[col];
#pragma unroll
        for (int mf = 0; mf < 8; ++mf) {
            const int rowb = m0 + wm + mf * 16 + ((lane >> 4) << 2);
#pragma unroll
            for (int rr = 0; rr < 4; ++rr) {
                Out[(size_t)(rowb + rr) * O_DIM + col] = acc[mf][nf][rr] + bj;
            }
        }
    }
#undef STAGE
#undef AFRAG
#undef BFRAG
#undef MFMA_Q
#undef KTILE
}

// ---------------------------------------------------------------------------
// Fused fallback (verified) — used if workspace too small or M%256 != 0
// ---------------------------------------------------------------------------
__global__ __launch_bounds__(256) void nf4_linear_kernel(
    const float* __restrict__ X,
    const int* __restrict__ Wp,
    const float* __restrict__ Smax,
    const float* __restrict__ Bias,
    float* __restrict__ Out,
    int M)
{
    __shared__ unsigned short Atile[BM * LDT];
    __shared__ unsigned short Btile[BN * LDT];
    __shared__ unsigned int   T2[256];

    const int t = threadIdx.x;
    const int m0 = blockIdx.x * BM;
    const int n0 = blockIdx.y * BN;

    {
        unsigned int hi = (unsigned int)bf16_rne(nf4_val(t >> 4));
        unsigned int lo = (unsigned int)bf16_rne(nf4_val(t & 15));
        T2[t] = hi | (lo << 16);
    }
    __syncthreads();

    const int lane = t & 63;
    const int wave = t >> 6;
    const int wm = (wave >> 1) * 64;
    const int wn = (wave & 1) * 64;
    const int ar = t >> 3;
    const int ach = t & 7;

    float4v acc[4][4] = {};

    for (int s = 0; s < K_DIM / BK; ++s) {
        const int kt = s * BK;
        float4v a0[4], a1[4]; uint4 wL[4]; float sc[4];
#pragma unroll
        for (int i = 0; i < 4; ++i) {
            const int row = ar + 32 * i;
            const float* ap = X + (size_t)(m0 + row) * K_DIM + kt + ach * 8;
            a0[i] = *(const float4v*)ap;
            a1[i] = *(const float4v*)(ap + 4);
            wL[i] = *(const uint4*)(Wp + (size_t)(n0 + row) * KP + (kt >> 1) + ach * 4);
            sc[i] = Smax[(n0 + row) * NBLK + s];
        }
#pragma unroll
        for (int i = 0; i < 4; ++i) {
            const int row = ar + 32 * i;
            uint4 av;
            av.x = pack_bf16x2(a0[i].x, a0[i].y);
            av.y = pack_bf16x2(a0[i].z, a0[i].w);
            av.z = pack_bf16x2(a1[i].x, a1[i].y);
            av.w = pack_bf16x2(a1[i].z, a1[i].w);
            *(uint4*)&Atile[row * LDT + ach * 8] = av;

            const float s0 = sc[i];
            unsigned int wv[4] = {(unsigned int)wL[i].x, (unsigned int)wL[i].y,
                                  (unsigned int)wL[i].z, (unsigned int)wL[i].w};
            unsigned int od[4];
#pragma unroll
            for (int j = 0; j < 4; ++j) {
                const unsigned int pair = T2[wv[j] & 0xFFu];
                const float fe = __uint_as_float(pair << 16) * s0;
                const float fo = __uint_as_float(pair & 0xFFFF0000u) * s0;
                od[j] = pack_bf16x2(fe, fo);
            }
            uint4 ov; ov.x = od[0]; ov.y = od[1]; ov.z = od[2]; ov.w = od[3];
            *(uint4*)&Btile[row * LDT + ach * 8] = ov;
        }
        __syncthreads();

#pragma unroll
        for (int k2 = 0; k2 < 2; ++k2) {
            const int ks = k2 * 32 + (lane >> 4) * 8;
            short8 afv[4], bfv[4];
#pragma unroll
            for (int i = 0; i < 4; ++i)
                afv[i] = *(const short8*)&Atile[(wm + i * 16 + (lane & 15)) * LDT + ks];
#pragma unroll
            for (int j = 0; j < 4; ++j)
                bfv[j] = *(const short8*)&Btile[(wn + j * 16 + (lane & 15)) * LDT + ks];
#pragma unroll
            for (int i = 0; i < 4; ++i)
#pragma unroll
                for (int j = 0; j < 4; ++j)
                    acc[i][j] = __builtin_amdgcn_mfma_f32_16x16x32_bf16(
                        afv[i], bfv[j], acc[i][j], 0, 0, 0);
        }
        __syncthreads();
    }

#pragma unroll
    for (int j = 0; j < 4; ++j) {
        const int col = n0 + wn + j * 16 + (lane & 15);
        const float bj = Bias[col];
#pragma unroll
        for (int i = 0; i < 4; ++i) {
            const int rowb = m0 + wm + i * 16 + ((lane >> 4) << 2);
#pragma unroll
            for (int rr = 0; rr < 4; ++rr) {
                Out[(size_t)(rowb + rr) * O_DIM + col] = acc[i][j][rr] + bj;
            }
        }
    }
}

extern "C" void kernel_launch(void* const* d_in, const int* in_sizes, int n_in,
                              void* d_out, int out_size, void* d_ws, size_t ws_size,
                              hipStream_t stream) {
    const float* X    = (const float*)d_in[0];
    const int*   Wp   = (const int*)d_in[1];
    const float* Smax = (const float*)d_in[2];
    const float* Bias = (const float*)d_in[3];
    float*       Out  = (float*)d_out;

    const int M = in_sizes[0] / K_DIM;   // 4096

    const size_t xb_bytes = (size_t)M * K_DIM * sizeof(unsigned short);      // 33.5 MB
    const size_t wb_bytes = (size_t)O_DIM * K_DIM * sizeof(unsigned short);  // 90.2 MB

    if (ws_size >= xb_bytes + wb_bytes && (M % BM2) == 0) {
        unsigned short* Xb = (unsigned short*)d_ws;
        unsigned short* Wb = (unsigned short*)((char*)d_ws + xb_bytes);

        const int nchunk_x = (M * K_DIM) / 8;        // 2,097,152
        const int nchunk_w = O_DIM * (KP / 4);       // 5,636,096
        prep_kernel<<<dim3(2048), dim3(256), 0, stream>>>(
            X, Xb, nchunk_x, Wp, Smax, Wb, nchunk_w);

        const int nwg = (M / BM2) * (O_DIM / BN2);    // 16*43 = 688, divisible by 8
        gemm_bf16_256<<<dim3(nwg), dim3(512), 0, stream>>>(Xb, Wb, Bias, Out, M);
    } else {
        dim3 grid(M / BM, O_DIM / BN);
        nf4_linear_kernel<<<grid, dim3(256), 0, stream>>>(X, Wp, Smax, Bias, Out, M);
    }
}

// Round 7
// 644.390 us; speedup vs baseline: 1.0024x; 1.0024x over previous
//
#include <hip/hip_runtime.h>

typedef __attribute__((ext_vector_type(8))) short short8;
typedef __attribute__((ext_vector_type(4))) float float4v;
typedef unsigned int u32;

#define K_DIM 4096
#define O_DIM 11008
#define KP    2048   // packed int32 per output row (1 byte of codes per int32)
#define NBLK  64     // absmax blocks per row
#define BK    64
#define NT2   (K_DIM / BK)   // 64 K-tiles
#define BM2   256
#define BN2   256
// fused-fallback geometry
#define BM    128
#define BN    128
#define LDT   72

// NF4 table via immediate-literal select tree (no device globals).
__device__ __forceinline__ float nf4_val(int c) {
    float v = -1.0f;
    v = (c == 1)  ? -0.6961928009986877f   : v;
    v = (c == 2)  ? -0.5250730514526367f   : v;
    v = (c == 3)  ? -0.39491748809814453f  : v;
    v = (c == 4)  ? -0.28444138169288635f  : v;
    v = (c == 5)  ? -0.18477343022823334f  : v;
    v = (c == 6)  ? -0.09105003625154495f  : v;
    v = (c == 7)  ? 0.0f                   : v;
    v = (c == 8)  ? 0.07958029955625534f   : v;
    v = (c == 9)  ? 0.16093020141124725f   : v;
    v = (c == 10) ? 0.24611230194568634f   : v;
    v = (c == 11) ? 0.33791524171829224f   : v;
    v = (c == 12) ? 0.44070982933044434f   : v;
    v = (c == 13) ? 0.5626170039176941f    : v;
    v = (c == 14) ? 0.8072066307067871f    : v;
    v = (c == 15) ? 1.0f                   : v;
    return v;
}

__device__ __forceinline__ unsigned short bf16_rne(float f) {
    unsigned int u = __float_as_uint(f);
    u = (u + 0x7FFFu + ((u >> 16) & 1u)) >> 16;
    return (unsigned short)u;
}

__device__ __forceinline__ unsigned int pack_bf16x2(float lo_k, float hi_k) {
    return (unsigned int)bf16_rne(lo_k) | ((unsigned int)bf16_rne(hi_k) << 16);
}

// async global->LDS, 16 B per lane; LDS dest is wave-uniform base + lane*16.
__device__ __forceinline__ void gload_lds16(const unsigned short* g, unsigned short* l) {
    __builtin_amdgcn_global_load_lds((const __attribute__((address_space(1))) u32*)g,
                                     (__attribute__((address_space(3))) u32*)l,
                                     16, 0, 0);
}

// ---------------------------------------------------------------------------
// Fused prep: (a) NF4 W -> bf16 (dequantized ONCE), (b) X f32 -> bf16.
// ---------------------------------------------------------------------------
__global__ __launch_bounds__(256) void prep_kernel(
    const float* __restrict__ X, unsigned short* __restrict__ Xb, int nchunk_x,
    const int* __restrict__ Wp, const float* __restrict__ Smax,
    unsigned short* __restrict__ Wb, int nchunk_w)
{
    __shared__ unsigned int T2[256];   // byte -> packed bf16 pair (unscaled)
    {
        const int t = threadIdx.x;
        unsigned int hi = (unsigned int)bf16_rne(nf4_val(t >> 4));
        unsigned int lo = (unsigned int)bf16_rne(nf4_val(t & 15));
        T2[t] = hi | (lo << 16);
    }
    __syncthreads();

    const int stride = gridDim.x * 256;
    const int g0 = blockIdx.x * 256 + threadIdx.x;

    for (int idx = g0; idx < nchunk_w; idx += stride) {
        const int row = idx >> 9;        // output row
        const int c   = idx & 511;       // 16B chunk within row (8 bf16 out)

        uint4 wv = *(const uint4*)(Wp + (size_t)row * KP + c * 4);
        const float s0 = Smax[row * NBLK + (c >> 3)];
        unsigned int vv[4] = {wv.x, wv.y, wv.z, wv.w};
        unsigned int od[4];
#pragma unroll
        for (int j = 0; j < 4; ++j) {
            const unsigned int pair = T2[vv[j] & 0xFFu];
            const float fe = __uint_as_float(pair << 16) * s0;           // k even (hi nibble)
            const float fo = __uint_as_float(pair & 0xFFFF0000u) * s0;   // k odd  (lo nibble)
            od[j] = pack_bf16x2(fe, fo);
        }
        uint4 ov; ov.x = od[0]; ov.y = od[1]; ov.z = od[2]; ov.w = od[3];
        *(uint4*)(Wb + (size_t)row * K_DIM + c * 8) = ov;
    }

    for (int i = g0; i < nchunk_x; i += stride) {
        const float* p = X + (size_t)i * 8;
        float4v a = *(const float4v*)p;
        float4v b = *(const float4v*)(p + 4);
        uint4 o;
        o.x = pack_bf16x2(a.x, a.y);
        o.y = pack_bf16x2(a.z, a.w);
        o.z = pack_bf16x2(b.x, b.y);
        o.w = pack_bf16x2(b.z, b.w);
        *(uint4*)(Xb + (size_t)i * 8) = o;
    }
}

// ---------------------------------------------------------------------------
// Main GEMM: 256x256, 8-wave, 4-phase/K-tile counted-vmcnt schedule with
// ONE-PHASE-AHEAD fragment prefetch (round 7).
//
// Phase p: { s_barrier; issue ds_reads for phase p+1; issue 1 half-stage
//            (global_load_lds); 16 MFMA on regs loaded during phase p-1 }.
// LDS read latency hides under the previous MFMA cluster; compiler emits
// exact counted lgkmcnt before each MFMA cluster (no inline lgkm/sched_bar).
// Only P1's own frags (afc,bfc) are unhidden (cross-wave visibility forbids
// issuing them before the post-vmcnt barrier).
//
// Frag regs (static names, rule #20): afc/afn/bfc/bfn (16 frags, 64 VGPR).
//   P1: read bfc(h0),afc(h0,mf0-3),afn(h0,mf4-7); MFMA afc x bfc  -> acc0-3
//   P2: read bfn(h1),afc(h1,mf0-3);               MFMA afn x bfc  -> acc4-7
//   P3: read afn(h1,mf4-7);                       MFMA afc x bfn  -> acc0-3
//   P4: (no reads);                               MFMA afn x bfn  -> acc4-7
//
// vmcnt ledger (2 loads/thread/phase; sim-verified steady state):
//   VMW6 @P1-end: outstanding 10 -> 6, retires (u,A,k1),(u,B,k1)  [h1 reads
//     issue at P2, one phase earlier than round-6 -> wait moved P2->P1]
//   VMW8 @P4-end: outstanding 12 -> 8, retires (u+1,A,k0),(u+1,B,k0)
//   vmcnt BEFORE the following barrier => cross-wave visibility correct.
//   Tails: tile62 VMW6/VMW4; tile63 VMW0/none.
// WAR (stage over read region): every wave's lgkm wait precedes its next
// barrier, so all reads of a region complete block-wide >=1 barrier before
// any re-stage of it (verified per region; same argument as R3/R4).
//
// LDS map (shorts): buf b at b*32768; A k-half h at h*8192, B at +16384;
// row*32 + slot*8; swizzle slot' = slot ^ ((row>>1)&3) (0 conflicts, R4).
// ---------------------------------------------------------------------------
#define VMW8 asm volatile("s_waitcnt vmcnt(8)" ::: "memory")
#define VMW6 asm volatile("s_waitcnt vmcnt(6)" ::: "memory")
#define VMW4 asm volatile("s_waitcnt vmcnt(4)" ::: "memory")
#define VMW0 asm volatile("s_waitcnt vmcnt(0)" ::: "memory")
#define VMWNONE ((void)0)

__global__ __launch_bounds__(512, 2) void gemm_bf16_256(
    const unsigned short* __restrict__ Xb,   // [M][4096] bf16
    const unsigned short* __restrict__ Wb,   // [11008][4096] bf16
    const float* __restrict__ Bias,
    float* __restrict__ Out, int M)
{
    __shared__ unsigned short L[65536];   // 128 KiB

    const int t    = threadIdx.x;
    const int lane = t & 63;
    const int w    = t >> 6;             // 8 waves

    // XCD swizzle (gridDim.x divisible by 8)
    const int nm  = M / BM2;             // 16
    const int nwg = gridDim.x;           // 688
    const int wg  = (blockIdx.x & 7) * (nwg >> 3) + (blockIdx.x >> 3);
    const int m0  = (wg % nm) * BM2;
    const int n0  = (wg / nm) * BN2;

    const int wm = (w >> 2) * 128;       // wave M window (0/128)
    const int wn = (w & 3) * 64;         // wave N window (0..192)

    // staging: wave w stages rows [32w, 32w+32); lane -> (row=lane>>2,
    // slot=lane&3); source slot pre-swizzled with ((row>>1)&3).
    const int srow  = lane >> 2;
    const int sslot = (lane & 3) ^ ((lane >> 3) & 3);
    const unsigned short* srcA = Xb + (size_t)(m0 + w * 32 + srow) * K_DIM + sslot * 8;
    const unsigned short* srcB = Wb + (size_t)(n0 + w * 32 + srow) * K_DIM + sslot * 8;
    unsigned short* ldsA = &L[w * 1024];
    unsigned short* ldsB = &L[16384 + w * 1024];

    // fragment reads: row = (wm|wn) + f*16 + (lane&15); wanted slot = lane>>4;
    // stored slot = (lane>>4) ^ ((lane>>1)&3).  Base pointers -> imm offsets.
    const int rrow  = lane & 15;
    const int rslot = ((lane >> 4) ^ ((lane >> 1) & 3)) * 8;
    const unsigned short* pA0 = &L[(wm + rrow) * 32 + rslot];
    const unsigned short* pA1 = pA0 + 32768;
    const unsigned short* pB0 = &L[16384 + (wn + rrow) * 32 + rslot];
    const unsigned short* pB1 = pB0 + 32768;

#define STAGE(src, ldsbase, bufh, koff)                                          \
    do {                                                                         \
        gload_lds16((src) + (koff), (ldsbase) + (bufh));                         \
        gload_lds16((src) + 16 * K_DIM + (koff), (ldsbase) + (bufh) + 512);      \
    } while (0)

#define AFRAG(b, h, mf) (*(const short8*)(((b) ? pA1 : pA0) + (h) * 8192 + (mf) * 512))
#define BFRAG(b, h, nf) (*(const short8*)(((b) ? pB1 : pB0) + (h) * 8192 + (nf) * 512))

    float4v acc[8][4] = {};
    short8 afc[4], afn[4], bfc[4], bfn[4];

#define MFMA_Q(mbase, AF, BF)                                                     \
    __builtin_amdgcn_s_setprio(1);                                                \
    _Pragma("unroll") for (int mf = 0; mf < 4; ++mf)                              \
        _Pragma("unroll") for (int nf = 0; nf < 4; ++nf)                          \
            acc[(mbase) + mf][nf] = __builtin_amdgcn_mfma_f32_16x16x32_bf16(      \
                AF[mf], BF[nf], acc[(mbase) + mf][nf], 0, 0, 0);                  \
    __builtin_amdgcn_s_setprio(0)

// b_ MUST be a literal 0/1 (== u_&1) so all LDS addressing is immediate.
#define KTILE(u_, b_, S12_, S34_, VM1_, VM4_)                                     \
    {                                                                             \
        const int kt_ = (u_) * BK;                                                \
        /* P1: own frags (unhidden) + prefetch afn; MFMA acc0-3 (h0) */           \
        __builtin_amdgcn_s_barrier();                                             \
        if (S12_) STAGE(srcA, ldsA, ((b_) ^ 1) * 32768 + 8192, kt_ + BK + 32);    \
        _Pragma("unroll") for (int nf = 0; nf < 4; ++nf) bfc[nf] = BFRAG(b_, 0, nf); \
        _Pragma("unroll") for (int mf = 0; mf < 4; ++mf) afc[mf] = AFRAG(b_, 0, mf); \
        _Pragma("unroll") for (int mf = 0; mf < 4; ++mf) afn[mf] = AFRAG(b_, 0, mf + 4); \
        MFMA_Q(0, afc, bfc);                                                      \
        VM1_;                                                                     \
        /* P2: prefetch h1 (bfn + afc); MFMA acc4-7 (h0) */                       \
        __builtin_amdgcn_s_barrier();                                             \
        if (S12_) STAGE(srcB, ldsB, ((b_) ^ 1) * 32768 + 8192, kt_ + BK + 32);    \
        _Pragma("unroll") for (int nf = 0; nf < 4; ++nf) bfn[nf] = BFRAG(b_, 1, nf); \
        _Pragma("unroll") for (int mf = 0; mf < 4; ++mf) afc[mf] = AFRAG(b_, 1, mf); \
        MFMA_Q(4, afn, bfc);                                                      \
        /* P3: prefetch afn (h1 mf4-7); MFMA acc0-3 (h1) */                       \
        __builtin_amdgcn_s_barrier();                                             \
        if (S34_) STAGE(srcA, ldsA, (b_) * 32768, kt_ + 2 * BK);                  \
        _Pragma("unroll") for (int mf = 0; mf < 4; ++mf) afn[mf] = AFRAG(b_, 1, mf + 4); \
        MFMA_Q(0, afc, bfn);                                                      \
        /* P4: no reads; MFMA acc4-7 (h1) */                                      \
        __builtin_amdgcn_s_barrier();                                             \
        if (S34_) STAGE(srcB, ldsB, (b_) * 32768, kt_ + 2 * BK);                  \
        MFMA_Q(4, afn, bfn);                                                      \
        VM4_;                                                                     \
    }

    // ---- prologue: stage (0,k0),(0,k1),(1,k0); retire (0,k0) ----
    STAGE(srcA, ldsA, 0,            0);    // (0,A,k0)
    STAGE(srcB, ldsB, 0,            0);    // (0,B,k0)
    STAGE(srcA, ldsA, 8192,         32);   // (0,A,k1)
    STAGE(srcB, ldsB, 8192,         32);   // (0,B,k1)
    STAGE(srcA, ldsA, 32768,        64);   // (1,A,k0)
    STAGE(srcB, ldsB, 32768,        64);   // (1,B,k0)
    VMW8;                                   // before first barrier (in KTILE P1)

    // ---- steady loop (unrolled x2 so buffer index is literal) + tails ----
    for (int u = 0; u < NT2 - 2; u += 2) {
        KTILE(u,     0, true, true, VMW6, VMW8);
        KTILE(u + 1, 1, true, true, VMW6, VMW8);
    }
    KTILE(NT2 - 2, 0, true, false, VMW6, VMW4);
    KTILE(NT2 - 1, 1, false, false, VMW0, VMWNONE);

    // ---- epilogue: D col = lane&15, row = (lane>>4)*4 + reg ----
#pragma unroll
    for (int nf = 0; nf < 4; ++nf) {
        const int col = n0 + wn + nf * 16 + (lane & 15);
        const float bj = Bias[col];
#pragma unroll
        for (int mf = 0; mf < 8; ++mf) {
            const int rowb = m0 + wm + mf * 16 + ((lane >> 4) << 2);
#pragma unroll
            for (int rr = 0; rr < 4; ++rr) {
                Out[(size_t)(rowb + rr) * O_DIM + col] = acc[mf][nf][rr] + bj;
            }
        }
    }
#undef STAGE
#undef AFRAG
#undef BFRAG
#undef MFMA_Q
#undef KTILE
}

// ---------------------------------------------------------------------------
// Fused fallback (verified) — used if workspace too small or M%256 != 0
// ---------------------------------------------------------------------------
__global__ __launch_bounds__(256) void nf4_linear_kernel(
    const float* __restrict__ X,
    const int* __restrict__ Wp,
    const float* __restrict__ Smax,
    const float* __restrict__ Bias,
    float* __restrict__ Out,
    int M)
{
    __shared__ unsigned short Atile[BM * LDT];
    __shared__ unsigned short Btile[BN * LDT];
    __shared__ unsigned int   T2[256];

    const int t = threadIdx.x;
    const int m0 = blockIdx.x * BM;
    const int n0 = blockIdx.y * BN;

    {
        unsigned int hi = (unsigned int)bf16_rne(nf4_val(t >> 4));
        unsigned int lo = (unsigned int)bf16_rne(nf4_val(t & 15));
        T2[t] = hi | (lo << 16);
    }
    __syncthreads();

    const int lane = t & 63;
    const int wave = t >> 6;
    const int wm = (wave >> 1) * 64;
    const int wn = (wave & 1) * 64;
    const int ar = t >> 3;
    const int ach = t & 7;

    float4v acc[4][4] = {};

    for (int s = 0; s < K_DIM / BK; ++s) {
        const int kt = s * BK;
        float4v a0[4], a1[4]; uint4 wL[4]; float sc[4];
#pragma unroll
        for (int i = 0; i < 4; ++i) {
            const int row = ar + 32 * i;
            const float* ap = X + (size_t)(m0 + row) * K_DIM + kt + ach * 8;
            a0[i] = *(const float4v*)ap;
            a1[i] = *(const float4v*)(ap + 4);
            wL[i] = *(const uint4*)(Wp + (size_t)(n0 + row) * KP + (kt >> 1) + ach * 4);
            sc[i] = Smax[(n0 + row) * NBLK + s];
        }
#pragma unroll
        for (int i = 0; i < 4; ++i) {
            const int row = ar + 32 * i;
            uint4 av;
            av.x = pack_bf16x2(a0[i].x, a0[i].y);
            av.y = pack_bf16x2(a0[i].z, a0[i].w);
            av.z = pack_bf16x2(a1[i].x, a1[i].y);
            av.w = pack_bf16x2(a1[i].z, a1[i].w);
            *(uint4*)&Atile[row * LDT + ach * 8] = av;

            const float s0 = sc[i];
            unsigned int wv[4] = {(unsigned int)wL[i].x, (unsigned int)wL[i].y,
                                  (unsigned int)wL[i].z, (unsigned int)wL[i].w};
            unsigned int od[4];
#pragma unroll
            for (int j = 0; j < 4; ++j) {
                const unsigned int pair = T2[wv[j] & 0xFFu];
                const float fe = __uint_as_float(pair << 16) * s0;
                const float fo = __uint_as_float(pair & 0xFFFF0000u) * s0;
                od[j] = pack_bf16x2(fe, fo);
            }
            uint4 ov; ov.x = od[0]; ov.y = od[1]; ov.z = od[2]; ov.w = od[3];
            *(uint4*)&Btile[row * LDT + ach * 8] = ov;
        }
        __syncthreads();

#pragma unroll
        for (int k2 = 0; k2 < 2; ++k2) {
            const int ks = k2 * 32 + (lane >> 4) * 8;
            short8 afv[4], bfv[4];
#pragma unroll
            for (int i = 0; i < 4; ++i)
                afv[i] = *(const short8*)&Atile[(wm + i * 16 + (lane & 15)) * LDT + ks];
#pragma unroll
            for (int j = 0; j < 4; ++j)
                bfv[j] = *(const short8*)&Btile[(wn + j * 16 + (lane & 15)) * LDT + ks];
#pragma unroll
            for (int i = 0; i < 4; ++i)
#pragma unroll
                for (int j = 0; j < 4; ++j)
                    acc[i][j] = __builtin_amdgcn_mfma_f32_16x16x32_bf16(
                        afv[i], bfv[j], acc[i][j], 0, 0, 0);
        }
        __syncthreads();
    }

#pragma unroll
    for (int j = 0; j < 4; ++j) {
        const int col = n0 + wn + j * 16 + (lane & 15);
        const float bj = Bias[col];
#pragma unroll
        for (int i = 0; i < 4; ++i) {
            const int rowb = m0 + wm + i * 16 + ((lane >> 4) << 2);
#pragma unroll
            for (int rr = 0; rr < 4; ++rr) {
                Out[(size_t)(rowb + rr) * O_DIM + col] = acc[i][j][rr] + bj;
            }
        }
    }
}

extern "C" void kernel_launch(void* const* d_in, const int* in_sizes, int n_in,
                              void* d_out, int out_size, void* d_ws, size_t ws_size,
                              hipStream_t stream) {
    const float* X    = (const float*)d_in[0];
    const int*   Wp   = (const int*)d_in[1];
    const float* Smax = (const float*)d_in[2];
    const float* Bias = (const float*)d_in[3];
    float*       Out  = (float*)d_out;

    const int M = in_sizes[0] / K_DIM;   // 4096

    const size_t xb_bytes = (size_t)M * K_DIM * sizeof(unsigned short);      // 33.5 MB
    const size_t wb_bytes = (size_t)O_DIM * K_DIM * sizeof(unsigned short);  // 90.2 MB

    if (ws_size >= xb_bytes + wb_bytes && (M % BM2) == 0) {
        unsigned short* Xb = (unsigned short*)d_ws;
        unsigned short* Wb = (unsigned short*)((char*)d_ws + xb_bytes);

        const int nchunk_x = (M * K_DIM) / 8;        // 2,097,152
        const int nchunk_w = O_DIM * (KP / 4);       // 5,636,096
        prep_kernel<<<dim3(2048), dim3(256), 0, stream>>>(
            X, Xb, nchunk_x, Wp, Smax, Wb, nchunk_w);

        const int nwg = (M / BM2) * (O_DIM / BN2);    // 16*43 = 688, divisible by 8
        gemm_bf16_256<<<dim3(nwg), dim3(512), 0, stream>>>(Xb, Wb, Bias, Out, M);
    } else {
        dim3 grid(M / BM, O_DIM / BN);
        nf4_linear_kernel<<<grid, dim3(256), 0, stream>>>(X, Wp, Smax, Bias, Out, M);
    }
}

// Round 8
// 644.381 us; speedup vs baseline: 1.0024x; 1.0000x over previous
//
#include <hip/hip_runtime.h>

typedef __attribute__((ext_vector_type(8))) short short8;
typedef __attribute__((ext_vector_type(4))) float float4v;
typedef unsigned int u32;

#define K_DIM 4096
#define O_DIM 11008
#define KP    2048   // packed int32 per output row (1 byte of codes per int32)
#define NBLK  64     // absmax blocks per row
#define BK    64
#define NT2   (K_DIM / BK)   // 64 K-tiles
#define BM2   256
#define BN2   256
// fused-fallback geometry
#define BM    128
#define BN    128
#define LDT   72

// NF4 table via immediate-literal select tree (no device globals).
__device__ __forceinline__ float nf4_val(int c) {
    float v = -1.0f;
    v = (c == 1)  ? -0.6961928009986877f   : v;
    v = (c == 2)  ? -0.5250730514526367f   : v;
    v = (c == 3)  ? -0.39491748809814453f  : v;
    v = (c == 4)  ? -0.28444138169288635f  : v;
    v = (c == 5)  ? -0.18477343022823334f  : v;
    v = (c == 6)  ? -0.09105003625154495f  : v;
    v = (c == 7)  ? 0.0f                   : v;
    v = (c == 8)  ? 0.07958029955625534f   : v;
    v = (c == 9)  ? 0.16093020141124725f   : v;
    v = (c == 10) ? 0.24611230194568634f   : v;
    v = (c == 11) ? 0.33791524171829224f   : v;
    v = (c == 12) ? 0.44070982933044434f   : v;
    v = (c == 13) ? 0.5626170039176941f    : v;
    v = (c == 14) ? 0.8072066307067871f    : v;
    v = (c == 15) ? 1.0f                   : v;
    return v;
}

__device__ __forceinline__ unsigned short bf16_rne(float f) {
    unsigned int u = __float_as_uint(f);
    u = (u + 0x7FFFu + ((u >> 16) & 1u)) >> 16;
    return (unsigned short)u;
}

__device__ __forceinline__ unsigned int pack_bf16x2(float lo_k, float hi_k) {
    return (unsigned int)bf16_rne(lo_k) | ((unsigned int)bf16_rne(hi_k) << 16);
}

// async global->LDS, 16 B per lane; LDS dest is wave-uniform base + lane*16.
__device__ __forceinline__ void gload_lds16(const unsigned short* g, unsigned short* l) {
    __builtin_amdgcn_global_load_lds((const __attribute__((address_space(1))) u32*)g,
                                     (__attribute__((address_space(3))) u32*)l,
                                     16, 0, 0);
}

// ---------------------------------------------------------------------------
// Fused prep: (a) NF4 W -> bf16 (dequantized ONCE), (b) X f32 -> bf16.
// ---------------------------------------------------------------------------
__global__ __launch_bounds__(256) void prep_kernel(
    const float* __restrict__ X, unsigned short* __restrict__ Xb, int nchunk_x,
    const int* __restrict__ Wp, const float* __restrict__ Smax,
    unsigned short* __restrict__ Wb, int nchunk_w)
{
    __shared__ unsigned int T2[256];   // byte -> packed bf16 pair (unscaled)
    {
        const int t = threadIdx.x;
        unsigned int hi = (unsigned int)bf16_rne(nf4_val(t >> 4));
        unsigned int lo = (unsigned int)bf16_rne(nf4_val(t & 15));
        T2[t] = hi | (lo << 16);
    }
    __syncthreads();

    const int stride = gridDim.x * 256;
    const int g0 = blockIdx.x * 256 + threadIdx.x;

    for (int idx = g0; idx < nchunk_w; idx += stride) {
        const int row = idx >> 9;        // output row
        const int c   = idx & 511;       // 16B chunk within row (8 bf16 out)

        uint4 wv = *(const uint4*)(Wp + (size_t)row * KP + c * 4);
        const float s0 = Smax[row * NBLK + (c >> 3)];
        unsigned int vv[4] = {wv.x, wv.y, wv.z, wv.w};
        unsigned int od[4];
#pragma unroll
        for (int j = 0; j < 4; ++j) {
            const unsigned int pair = T2[vv[j] & 0xFFu];
            const float fe = __uint_as_float(pair << 16) * s0;           // k even (hi nibble)
            const float fo = __uint_as_float(pair & 0xFFFF0000u) * s0;   // k odd  (lo nibble)
            od[j] = pack_bf16x2(fe, fo);
        }
        uint4 ov; ov.x = od[0]; ov.y = od[1]; ov.z = od[2]; ov.w = od[3];
        *(uint4*)(Wb + (size_t)row * K_DIM + c * 8) = ov;
    }

    for (int i = g0; i < nchunk_x; i += stride) {
        const float* p = X + (size_t)i * 8;
        float4v a = *(const float4v*)p;
        float4v b = *(const float4v*)(p + 4);
        uint4 o;
        o.x = pack_bf16x2(a.x, a.y);
        o.y = pack_bf16x2(a.z, a.w);
        o.z = pack_bf16x2(b.x, b.y);
        o.w = pack_bf16x2(b.z, b.w);
        *(uint4*)(Xb + (size_t)i * 8) = o;
    }
}

// ---------------------------------------------------------------------------
// Main GEMM: 256x256, 8-wave, 4-phase/K-tile counted-vmcnt schedule with
// FULL one-phase-ahead fragment prefetch (round 8): ZERO own-phase ds_reads.
//
// Frag sets (static names, rule #20): afc/afn (h0 lo/hi), afc2/afn2 (h1
// lo/hi), bfc (h0), bfn (h1).  Schedule per tile u (buf b=u&1):
//   P4(u-1): reads bfc,afc = (u,h0)          [8 rd]  MFMA afn2 x bfn
//   P1(u):   reads afn  = (u,h0,mf4-7)       [4 rd]  MFMA afc  x bfc ; VMW6
//   P2(u):   reads bfn,afc2 = (u,h1)         [8 rd]  MFMA afn  x bfc
//   P3(u):   reads afn2 = (u,h1,mf4-7)       [4 rd]  MFMA afc2 x bfn ; VMW6
// Staging unchanged: P1/P2 stage (u+1,k1) A/B; P3/P4 stage (u+2,k0) A/B.
//
// vmcnt ledger (2 loads per stage; sim-verified):
//   VMW6 @P1-end: outstanding 10 -> 6, retires (u,A,k1),(u,B,k1)  -> P2 reads
//   VMW6 @P3-end: outstanding 10 -> 6, retires (u+1,A,k0),(u+1,B,k0) -> P4 reads
//   vmcnt sits BEFORE the following barrier => cross-wave visibility.
//   Prologue: 6 stages, VMW8 retires (0,k0); (0,k1) retired by P1-end(0).
//   Tails: u=62 VMW6/VMW4 (S34 off); u=63 VMW0/none (S12 off, P4-reads off).
// WAR audit: every region's re-stage is >=1 barrier after the block-wide
// lgkm-completion of its last reader (tight cases (b^1,h1,A)@P1-stage and
// (b^1,h0,A)@P3-stage verified one-barrier-separated).
//
// LDS map (shorts): buf b at b*32768; A k-half h at h*8192, B at +16384;
// row*32 + slot*8; swizzle slot' = slot ^ ((row>>1)&3) (0 conflicts, R4).
// ---------------------------------------------------------------------------
#define VMW8 asm volatile("s_waitcnt vmcnt(8)" ::: "memory")
#define VMW6 asm volatile("s_waitcnt vmcnt(6)" ::: "memory")
#define VMW4 asm volatile("s_waitcnt vmcnt(4)" ::: "memory")
#define VMW0 asm volatile("s_waitcnt vmcnt(0)" ::: "memory")
#define VMWNONE ((void)0)

__global__ __launch_bounds__(512, 2) void gemm_bf16_256(
    const unsigned short* __restrict__ Xb,   // [M][4096] bf16
    const unsigned short* __restrict__ Wb,   // [11008][4096] bf16
    const float* __restrict__ Bias,
    float* __restrict__ Out, int M)
{
    __shared__ unsigned short L[65536];   // 128 KiB

    const int t    = threadIdx.x;
    const int lane = t & 63;
    const int w    = t >> 6;             // 8 waves

    // XCD swizzle (gridDim.x divisible by 8)
    const int nm  = M / BM2;             // 16
    const int nwg = gridDim.x;           // 688
    const int wg  = (blockIdx.x & 7) * (nwg >> 3) + (blockIdx.x >> 3);
    const int m0  = (wg % nm) * BM2;
    const int n0  = (wg / nm) * BN2;

    const int wm = (w >> 2) * 128;       // wave M window (0/128)
    const int wn = (w & 3) * 64;         // wave N window (0..192)

    // staging: wave w stages rows [32w, 32w+32); lane -> (row=lane>>2,
    // slot=lane&3); source slot pre-swizzled with ((row>>1)&3).
    const int srow  = lane >> 2;
    const int sslot = (lane & 3) ^ ((lane >> 3) & 3);
    const unsigned short* srcA = Xb + (size_t)(m0 + w * 32 + srow) * K_DIM + sslot * 8;
    const unsigned short* srcB = Wb + (size_t)(n0 + w * 32 + srow) * K_DIM + sslot * 8;
    unsigned short* ldsA = &L[w * 1024];
    unsigned short* ldsB = &L[16384 + w * 1024];

    // fragment reads: row = (wm|wn) + f*16 + (lane&15); wanted slot = lane>>4;
    // stored slot = (lane>>4) ^ ((lane>>1)&3).  Base pointers -> imm offsets.
    const int rrow  = lane & 15;
    const int rslot = ((lane >> 4) ^ ((lane >> 1) & 3)) * 8;
    const unsigned short* pA0 = &L[(wm + rrow) * 32 + rslot];
    const unsigned short* pA1 = pA0 + 32768;
    const unsigned short* pB0 = &L[16384 + (wn + rrow) * 32 + rslot];
    const unsigned short* pB1 = pB0 + 32768;

#define STAGE(src, ldsbase, bufh, koff)                                          \
    do {                                                                         \
        gload_lds16((src) + (koff), (ldsbase) + (bufh));                         \
        gload_lds16((src) + 16 * K_DIM + (koff), (ldsbase) + (bufh) + 512);      \
    } while (0)

#define AFRAG(b, h, mf) (*(const short8*)(((b) ? pA1 : pA0) + (h) * 8192 + (mf) * 512))
#define BFRAG(b, h, nf) (*(const short8*)(((b) ? pB1 : pB0) + (h) * 8192 + (nf) * 512))

    float4v acc[8][4] = {};
    short8 afc[4], afn[4], afc2[4], afn2[4], bfc[4], bfn[4];

#define MFMA_Q(mbase, AF, BF)                                                     \
    __builtin_amdgcn_s_setprio(1);                                                \
    _Pragma("unroll") for (int mf = 0; mf < 4; ++mf)                              \
        _Pragma("unroll") for (int nf = 0; nf < 4; ++nf)                          \
            acc[(mbase) + mf][nf] = __builtin_amdgcn_mfma_f32_16x16x32_bf16(      \
                AF[mf], BF[nf], acc[(mbase) + mf][nf], 0, 0, 0);                  \
    __builtin_amdgcn_s_setprio(0)

// b_ MUST be a literal 0/1 (== u_&1) so all LDS addressing is immediate.
#define KTILE(u_, b_, S12_, S34_, RD4_, VM1_, VM3_)                               \
    {                                                                             \
        const int kt_ = (u_) * BK;                                                \
        /* P1: prefetch afn(u,h0 hi); MFMA afc x bfc (loaded last P4) */          \
        __builtin_amdgcn_s_barrier();                                             \
        if (S12_) STAGE(srcA, ldsA, ((b_) ^ 1) * 32768 + 8192, kt_ + BK + 32);    \
        _Pragma("unroll") for (int mf = 0; mf < 4; ++mf) afn[mf] = AFRAG(b_, 0, mf + 4); \
        MFMA_Q(0, afc, bfc);                                                      \
        VM1_;                                                                     \
        /* P2: prefetch (u,h1) lo: bfn + afc2; MFMA afn x bfc */                  \
        __builtin_amdgcn_s_barrier();                                             \
        if (S12_) STAGE(srcB, ldsB, ((b_) ^ 1) * 32768 + 8192, kt_ + BK + 32);    \
        _Pragma("unroll") for (int nf = 0; nf < 4; ++nf) bfn[nf] = BFRAG(b_, 1, nf); \
        _Pragma("unroll") for (int mf = 0; mf < 4; ++mf) afc2[mf] = AFRAG(b_, 1, mf); \
        MFMA_Q(4, afn, bfc);                                                      \
        /* P3: prefetch afn2(u,h1 hi); MFMA afc2 x bfn */                         \
        __builtin_amdgcn_s_barrier();                                             \
        if (S34_) STAGE(srcA, ldsA, (b_) * 32768, kt_ + 2 * BK);                  \
        _Pragma("unroll") for (int mf = 0; mf < 4; ++mf) afn2[mf] = AFRAG(b_, 1, mf + 4); \
        MFMA_Q(0, afc2, bfn);                                                     \
        VM3_;                                                                     \
        /* P4: prefetch NEXT tile (u+1,h0) lo: bfc + afc; MFMA afn2 x bfn */      \
        __builtin_amdgcn_s_barrier();                                             \
        if (S34_) STAGE(srcB, ldsB, (b_) * 32768, kt_ + 2 * BK);                  \
        if (RD4_) {                                                               \
            _Pragma("unroll") for (int nf = 0; nf < 4; ++nf) bfc[nf] = BFRAG((b_) ^ 1, 0, nf); \
            _Pragma("unroll") for (int mf = 0; mf < 4; ++mf) afc[mf] = AFRAG((b_) ^ 1, 0, mf); \
        }                                                                         \
        MFMA_Q(4, afn2, bfn);                                                     \
    }

    // ---- prologue: stage (0,k0),(0,k1),(1,k0); retire (0,k0); read (0,h0) ----
    STAGE(srcA, ldsA, 0,            0);    // (0,A,k0)
    STAGE(srcB, ldsB, 0,            0);    // (0,B,k0)
    STAGE(srcA, ldsA, 8192,         32);   // (0,A,k1)
    STAGE(srcB, ldsB, 8192,         32);   // (0,B,k1)
    STAGE(srcA, ldsA, 32768,        64);   // (1,A,k0)
    STAGE(srcB, ldsB, 32768,        64);   // (1,B,k0)
    VMW8;                                  // retire (0,A,k0),(0,B,k0)
    __builtin_amdgcn_s_barrier();          // cross-wave visibility for (0,k0)
#pragma unroll
    for (int nf = 0; nf < 4; ++nf) bfc[nf] = BFRAG(0, 0, nf);
#pragma unroll
    for (int mf = 0; mf < 4; ++mf) afc[mf] = AFRAG(0, 0, mf);

    // ---- steady loop (unrolled x2 so buffer index is literal) + tails ----
    for (int u = 0; u < NT2 - 2; u += 2) {
        KTILE(u,     0, true, true, true, VMW6, VMW6);
        KTILE(u + 1, 1, true, true, true, VMW6, VMW6);
    }
    KTILE(NT2 - 2, 0, true,  false, true,  VMW6, VMW4);
    KTILE(NT2 - 1, 1, false, false, false, VMW0, VMWNONE);

    // ---- epilogue: D col = lane&15, row = (lane>>4)*4 + reg ----
#pragma unroll
    for (int nf = 0; nf < 4; ++nf) {
        const int col = n0 + wn + nf * 16 + (lane & 15);
        const float bj = Bias[col];
#pragma unroll
        for (int mf = 0; mf < 8; ++mf) {
            const int rowb = m0 + wm + mf * 16 + ((lane >> 4) << 2);
#pragma unroll
            for (int rr = 0; rr < 4; ++rr) {
                Out[(size_t)(rowb + rr) * O_DIM + col] = acc[mf][nf][rr] + bj;
            }
        }
    }
#undef STAGE
#undef AFRAG
#undef BFRAG
#undef MFMA_Q
#undef KTILE
}

// ---------------------------------------------------------------------------
// Fused fallback (verified) — used if workspace too small or M%256 != 0
// ---------------------------------------------------------------------------
__global__ __launch_bounds__(256) void nf4_linear_kernel(
    const float* __restrict__ X,
    const int* __restrict__ Wp,
    const float* __restrict__ Smax,
    const float* __restrict__ Bias,
    float* __restrict__ Out,
    int M)
{
    __shared__ unsigned short Atile[BM * LDT];
    __shared__ unsigned short Btile[BN * LDT];
    __shared__ unsigned int   T2[256];

    const int t = threadIdx.x;
    const int m0 = blockIdx.x * BM;
    const int n0 = blockIdx.y * BN;

    {
        unsigned int hi = (unsigned int)bf16_rne(nf4_val(t >> 4));
        unsigned int lo = (unsigned int)bf16_rne(nf4_val(t & 15));
        T2[t] = hi | (lo << 16);
    }
    __syncthreads();

    const int lane = t & 63;
    const int wave = t >> 6;
    const int wm = (wave >> 1) * 64;
    const int wn = (wave & 1) * 64;
    const int ar = t >> 3;
    const int ach = t & 7;

    float4v acc[4][4] = {};

    for (int s = 0; s < K_DIM / BK; ++s) {
        const int kt = s * BK;
        float4v a0[4], a1[4]; uint4 wL[4]; float sc[4];
#pragma unroll
        for (int i = 0; i < 4; ++i) {
            const int row = ar + 32 * i;
            const float* ap = X + (size_t)(m0 + row) * K_DIM + kt + ach * 8;
            a0[i] = *(const float4v*)ap;
            a1[i] = *(const float4v*)(ap + 4);
            wL[i] = *(const uint4*)(Wp + (size_t)(n0 + row) * KP + (kt >> 1) + ach * 4);
            sc[i] = Smax[(n0 + row) * NBLK + s];
        }
#pragma unroll
        for (int i = 0; i < 4; ++i) {
            const int row = ar + 32 * i;
            uint4 av;
            av.x = pack_bf16x2(a0[i].x, a0[i].y);
            av.y = pack_bf16x2(a0[i].z, a0[i].w);
            av.z = pack_bf16x2(a1[i].x, a1[i].y);
            av.w = pack_bf16x2(a1[i].z, a1[i].w);
            *(uint4*)&Atile[row * LDT + ach * 8] = av;

            const float s0 = sc[i];
            unsigned int wv[4] = {(unsigned int)wL[i].x, (unsigned int)wL[i].y,
                                  (unsigned int)wL[i].z, (unsigned int)wL[i].w};
            unsigned int od[4];
#pragma unroll
            for (int j = 0; j < 4; ++j) {
                const unsigned int pair = T2[wv[j] & 0xFFu];
                const float fe = __uint_as_float(pair << 16) * s0;
                const float fo = __uint_as_float(pair & 0xFFFF0000u) * s0;
                od[j] = pack_bf16x2(fe, fo);
            }
            uint4 ov; ov.x = od[0]; ov.y = od[1]; ov.z = od[2]; ov.w = od[3];
            *(uint4*)&Btile[row * LDT + ach * 8] = ov;
        }
        __syncthreads();

#pragma unroll
        for (int k2 = 0; k2 < 2; ++k2) {
            const int ks = k2 * 32 + (lane >> 4) * 8;
            short8 afv[4], bfv[4];
#pragma unroll
            for (int i = 0; i < 4; ++i)
                afv[i] = *(const short8*)&Atile[(wm + i * 16 + (lane & 15)) * LDT + ks];
#pragma unroll
            for (int j = 0; j < 4; ++j)
                bfv[j] = *(const short8*)&Btile[(wn + j * 16 + (lane & 15)) * LDT + ks];
#pragma unroll
            for (int i = 0; i < 4; ++i)
#pragma unroll
                for (int j = 0; j < 4; ++j)
                    acc[i][j] = __builtin_amdgcn_mfma_f32_16x16x32_bf16(
                        afv[i], bfv[j], acc[i][j], 0, 0, 0);
        }
        __syncthreads();
    }

#pragma unroll
    for (int j = 0; j < 4; ++j) {
        const int col = n0 + wn + j * 16 + (lane & 15);
        const float bj = Bias[col];
#pragma unroll
        for (int i = 0; i < 4; ++i) {
            const int rowb = m0 + wm + i * 16 + ((lane >> 4) << 2);
#pragma unroll
            for (int rr = 0; rr < 4; ++rr) {
                Out[(size_t)(rowb + rr) * O_DIM + col] = acc[i][j][rr] + bj;
            }
        }
    }
}

extern "C" void kernel_launch(void* const* d_in, const int* in_sizes, int n_in,
                              void* d_out, int out_size, void* d_ws, size_t ws_size,
                              hipStream_t stream) {
    const float* X    = (const float*)d_in[0];
    const int*   Wp   = (const int*)d_in[1];
    const float* Smax = (const float*)d_in[2];
    const float* Bias = (const float*)d_in[3];
    float*       Out  = (float*)d_out;

    const int M = in_sizes[0] / K_DIM;   // 4096

    const size_t xb_bytes = (size_t)M * K_DIM * sizeof(unsigned short);      // 33.5 MB
    const size_t wb_bytes = (size_t)O_DIM * K_DIM * sizeof(unsigned short);  // 90.2 MB

    if (ws_size >= xb_bytes + wb_bytes && (M % BM2) == 0) {
        unsigned short* Xb = (unsigned short*)d_ws;
        unsigned short* Wb = (unsigned short*)((char*)d_ws + xb_bytes);

        const int nchunk_x = (M * K_DIM) / 8;        // 2,097,152
        const int nchunk_w = O_DIM * (KP / 4);       // 5,636,096
        prep_kernel<<<dim3(2048), dim3(256), 0, stream>>>(
            X, Xb, nchunk_x, Wp, Smax, Wb, nchunk_w);

        const int nwg = (M / BM2) * (O_DIM / BN2);    // 16*43 = 688, divisible by 8
        gemm_bf16_256<<<dim3(nwg), dim3(512), 0, stream>>>(Xb, Wb, Bias, Out, M);
    } else {
        dim3 grid(M / BM, O_DIM / BN);
        nf4_linear_kernel<<<grid, dim3(256), 0, stream>>>(X, Wp, Smax, Bias, Out, M);
    }
}